// Round 6
// baseline (15369.632 us; speedup 1.0000x reference)
//
#include <hip/hip_runtime.h>
#include <hip/hip_fp16.h>

// SoftRR: n=1024, m=8192, rounds=8, TAU=1.0
//   scan over 8192 rows (V tiled x8):
//     y = softmax((row - min(row) + 1) * c);  c = (1-y)*c
//   pi[i][j] = sum over rounds of y
//
// R10: multi-CU dataflow scan. R4-R9 established: one CU is issue-saturated
// at ~1000 cy/step; every sync/instruction micro-opt bounced off ~1220 cy.
// The serial dependence is only through the SCALAR S_s, so spread columns
// over 16 CUs and pay one cross-CU scalar round trip per step:
//   - 16 blocks x 256 thr (4 waves), 2 cols/thread. 64 waves total.
//   - global ring of 4 x 64 seq-tagged 8-B slots (R9 protocol at AGENT
//     scope). lane63 of each wave publishes (partial, tag=s+2) as one 8-B
//     relaxed atomic store; every wave polls all 64 slots with ONE coalesced
//     64-lane load + __any, then 6-dpp full-wave sum -> S. No barriers, no
//     LDS, 1 wave/SIMD (zero issue contention).
//   - skew <= 1 step (cannot pass step s without all step-s partials) =>
//     ring 4 safe; tags monotone; ring re-zeroed EVERY launch in prep16
//     (stale tags from a previous bench iteration would satisfy polls).
//   - per-SIMD issue ~100 cy; step ~ RT_LLC + ~150 cy. Predicted scan
//     1.9-3.2 ms vs 4.16 ms single-CU.

#define N_ROWS 1024
#define M_COLS 8192
#define STEPS  8192
#define LOG2E  1.4426950408889634f
#define NBLK   16
#define TPB_MC 256

using half8  = __attribute__((ext_vector_type(8))) _Float16;
using half2v = __attribute__((ext_vector_type(2))) _Float16;

__device__ __forceinline__ float fast_exp2(float x) {
#if __has_builtin(__builtin_amdgcn_exp2f)
  return __builtin_amdgcn_exp2f(x);
#else
  return exp2f(x);
#endif
}
__device__ __forceinline__ float fast_rcp(float x) {
#if __has_builtin(__builtin_amdgcn_rcpf)
  return __builtin_amdgcn_rcpf(x);
#else
  return 1.0f / x;
#endif
}
__device__ __forceinline__ unsigned pack_f16_u32(float y0, float y1) {
  return __builtin_bit_cast(unsigned, __builtin_amdgcn_cvt_pkrtz(y0, y1));
}

template <int CTRL>
__device__ __forceinline__ float dpp_add(float x) {
  int yi = __builtin_amdgcn_update_dpp(0, __builtin_bit_cast(int, x),
                                       CTRL, 0xf, 0xf, true);
  return x + __builtin_bit_cast(float, yi);
}

// full 64-lane sum; result valid in lane 63
__device__ __forceinline__ float wave_sum_to_lane63(float x) {
  x = dpp_add<0x111>(x);  // row_shr:1
  x = dpp_add<0x112>(x);  // row_shr:2
  x = dpp_add<0x114>(x);  // row_shr:4
  x = dpp_add<0x118>(x);  // row_shr:8   -> lane15 of each row = row sum
  x = dpp_add<0x142>(x);  // row_bcast15
  x = dpp_add<0x143>(x);  // row_bcast31 -> lane63 = total
  return x;
}

// ---------------- rowmin: one block per row ----------------
__global__ void softrr_rowmin(const float* __restrict__ V, float* __restrict__ rmin) {
  const int row = blockIdx.x;
  const float* p = V + (size_t)row * M_COLS;
  float m = 1e30f;
  for (int j = threadIdx.x; j < M_COLS; j += 256) m = fminf(m, p[j]);
#pragma unroll
  for (int off = 32; off; off >>= 1) m = fminf(m, __shfl_xor(m, off, 64));
  __shared__ float sm[4];
  if ((threadIdx.x & 63) == 0) sm[threadIdx.x >> 6] = m;
  __syncthreads();
  if (threadIdx.x == 0) {
    rmin[row] = fminf(fminf(sm[0], sm[1]), fminf(sm[2], sm[3]));
  }
}

// ---------------- prep (f16): a = (V - rowmin + 1) * log2e; zero sync ring --
__global__ void softrr_prep16(const float* __restrict__ V, const float* __restrict__ rmin,
                              __half* __restrict__ A,
                              unsigned long long* __restrict__ ringz) {
  // re-zero the 4x64 tagged slots every launch (stale tags would satisfy polls)
  if (blockIdx.x == 0 && threadIdx.x < 256) ringz[threadIdx.x] = 0ULL;

  const int idx8 = blockIdx.x * 256 + threadIdx.x;   // 1M half8 groups
  const int row = idx8 >> 10;                        // 1024 half8 per row
  const float mn = rmin[row];
  const float4* v4 = (const float4*)V;
  float4 va = v4[2 * idx8];
  float4 vb = v4[2 * idx8 + 1];
  half8 o;
  o[0] = (_Float16)((va.x - mn + 1.0f) * LOG2E);
  o[1] = (_Float16)((va.y - mn + 1.0f) * LOG2E);
  o[2] = (_Float16)((va.z - mn + 1.0f) * LOG2E);
  o[3] = (_Float16)((va.w - mn + 1.0f) * LOG2E);
  o[4] = (_Float16)((vb.x - mn + 1.0f) * LOG2E);
  o[5] = (_Float16)((vb.y - mn + 1.0f) * LOG2E);
  o[6] = (_Float16)((vb.z - mn + 1.0f) * LOG2E);
  o[7] = (_Float16)((vb.w - mn + 1.0f) * LOG2E);
  ((half8*)A)[idx8] = o;
}

// ---------------- R10 multi-CU step body ----------------
// Ring protocol: partials of e_s live in ring[s&3][slot] tagged s+1.
// Step s (POS = s&3 compile-time):
//   window: store y_{s-1}, prefetch A(s+3)        (independent of S_s)
//   poll ring[POS]: lane L loads slot L (64 slots, one coalesced load)
//     until __any(tag != s+1) fails -> 6-dpp wave sum -> S_s -> Sinv
//   y = e*Sinv; c' = fma(-y,c,c); e' = exp2((float)a * c')
//   l = e0'+e1' -> wave_sum -> lane63 publishes (l, s+2) -> ring[(POS+1)&3]
//   pack y -> o (off critical path)
template <int POS>
__device__ __forceinline__ void rr_step_mc(
    int s, const unsigned acur, unsigned& adst,
    float& e0, float& e1, float& c0, float& c1, unsigned& o,
    const unsigned* __restrict__ A2, unsigned* __restrict__ R2,
    unsigned long long (*__restrict__ ring)[64], int cp, int lane, int slot)
{
  // ---- window: independent of S_s ----
  R2[(size_t)((s - 1) & (STEPS - 1)) * 4096 + cp] = o;   // y_{s-1}
  adst = A2[((s + 3) & (N_ROWS - 1)) * 4096 + cp];       // prefetch A row s+3

  // ---- poll all 64 wave-partials of e_s (tag s+1) ----
  const unsigned want = (unsigned)(s + 1);
  unsigned long long v;
  do {
    v = __hip_atomic_load(&ring[POS][lane], __ATOMIC_RELAXED,
                          __HIP_MEMORY_SCOPE_AGENT);
  } while (__any((unsigned)(v >> 32) != want));
  float x = __uint_as_float((unsigned)v);

  // sum the 64 slot values -> S
  x = wave_sum_to_lane63(x);
  const float S = __builtin_bit_cast(
      float, __builtin_amdgcn_readlane(__builtin_bit_cast(int, x), 63));
  const float Sinv = fast_rcp(S);

  // ---- chain: y = e*Sinv; c' = c - y*c; e' = exp2(a*c') ----
  const half2v a2 = __builtin_bit_cast(half2v, acur);
  const float y0 = e0 * Sinv;
  const float y1 = e1 * Sinv;
  c0 = __builtin_fmaf(-y0, c0, c0);
  c1 = __builtin_fmaf(-y1, c1, c1);
  e0 = fast_exp2(__builtin_fmaf((float)a2[0], c0, 0.0f));   // v_fma_mix
  e1 = fast_exp2(__builtin_fmaf((float)a2[1], c1, 0.0f));
  float l = e0 + e1;
  l = wave_sum_to_lane63(l);
  if (lane == 63) {
    const unsigned long long pv =
        ((unsigned long long)(unsigned)(s + 2) << 32) |
        (unsigned long long)__builtin_bit_cast(unsigned, l);
    __hip_atomic_store(&ring[(POS + 1) & 3][slot], pv, __ATOMIC_RELAXED,
                       __HIP_MEMORY_SCOPE_AGENT);
  }

  // ---- tail (off critical path): pack y_s for next-step store ----
  o = pack_f16_u32(y0, y1);
}

// ---------------- main scan (R10): 16 blocks x 256 thr, 2 cols/thread ------
__global__ void __launch_bounds__(TPB_MC) softrr_scan_mc(
    const __half* __restrict__ Ah, __half* __restrict__ Rh,
    unsigned long long* __restrict__ ringp) {
  const int b = blockIdx.x;           // 0..15
  const int t = threadIdx.x;          // 0..255
  const int wavei = t >> 6;           // 0..3
  const int lane = t & 63;
  const int slot = (b << 2) | wavei;  // 0..63
  const int cp = b * 256 + t;         // u32 column-pair index, 0..4095

  unsigned long long (*__restrict__ ring)[64] =
      (unsigned long long (*)[64])ringp;
  const unsigned* __restrict__ A2 = (const unsigned*)Ah;   // [1024][4096]
  unsigned* __restrict__ R2 = (unsigned*)Rh;               // [8192][4096]

  float c0 = 1.0f, c1 = 1.0f;

  // prologue: row 0 -> e_0; rows 1,2 into the A ring
  const unsigned r0 = A2[cp];
  unsigned pA = A2[4096 + cp];        // row 1
  unsigned pB = 0; pB = A2[2 * 4096 + cp];  // row 2
  unsigned pC, pD;

  float e0, e1;
  {
    const half2v a2 = __builtin_bit_cast(half2v, r0);
    e0 = fast_exp2((float)a2[0]);     // c_0 = 1
    e1 = fast_exp2((float)a2[1]);
    float l = e0 + e1;
    l = wave_sum_to_lane63(l);
    if (lane == 63) {
      const unsigned long long pv =
          (1ULL << 32) | (unsigned long long)__builtin_bit_cast(unsigned, l);
      __hip_atomic_store(&ring[0][slot], pv, __ATOMIC_RELAXED,
                         __HIP_MEMORY_SCOPE_AGENT);
    }
  }
  unsigned o = 0u;   // garbage y_{-1}; only reaches row 8191 (re-flushed)

  // x4 unroll: A-buffer cycle period 4, ring index compile-time
  for (int s = 0; s < STEPS; s += 4) {
    rr_step_mc<0>(s + 0, pA, pC, e0, e1, c0, c1, o, A2, R2, ring, cp, lane, slot);
    rr_step_mc<1>(s + 1, pB, pD, e0, e1, c0, c1, o, A2, R2, ring, cp, lane, slot);
    rr_step_mc<2>(s + 2, pC, pA, e0, e1, c0, c1, o, A2, R2, ring, cp, lane, slot);
    rr_step_mc<3>(s + 3, pD, pB, e0, e1, c0, c1, o, A2, R2, ring, cp, lane, slot);
  }

  // flush y_{8191} (packed in o; also overwrites the s=0 garbage row)
  R2[(size_t)(STEPS - 1) * 4096 + cp] = o;
}

// ---------------- epilogue: out[i][j] = sum_r R[r*1024+i][j] (f32) ----------------
__global__ void softrr_sum8(const __half* __restrict__ Rh, float* __restrict__ out) {
  const int idx8 = blockIdx.x * 256 + threadIdx.x;   // 1M half8 outputs
  const half8* R8 = (const half8*)Rh;
  float acc[8];
  {
    half8 v = R8[idx8];
#pragma unroll
    for (int k = 0; k < 8; ++k) acc[k] = (float)v[k];
  }
#pragma unroll
  for (int r = 1; r < 8; ++r) {
    half8 v = R8[(size_t)r * 1024 * 1024 + idx8];
#pragma unroll
    for (int k = 0; k < 8; ++k) acc[k] += (float)v[k];
  }
  ((float4*)out)[2 * idx8]     = make_float4(acc[0], acc[1], acc[2], acc[3]);
  ((float4*)out)[2 * idx8 + 1] = make_float4(acc[4], acc[5], acc[6], acc[7]);
}

// ---------------- fallback B: f32 direct (tiny ws) ----------------
__global__ void __launch_bounds__(1024) softrr_scan_b(const float* __restrict__ V,
                                                      const float* __restrict__ rmin,
                                                      float* __restrict__ out) {
  const int t = threadIdx.x;
  const int wave = t >> 6;
  const int lane = t & 63;
  __shared__ float partials[2][16];
  __shared__ float smin[N_ROWS];
  smin[t] = rmin[t];
  __syncthreads();
  const float4* __restrict__ V4 = (const float4*)V;
  float4* O4 = (float4*)out;
  float c[8];
#pragma unroll
  for (int k = 0; k < 8; ++k) c[k] = 1.0f;
  float4 va = V4[2 * t], vb = V4[2 * t + 1];
  float4 pa, pb;
  for (int s = 0; s < STEPS; ++s) {
    const int i = s & (N_ROWS - 1);
    const int r = s >> 10;
    const int in_ = (s + 1) & (N_ROWS - 1);
    float4 van = V4[in_ * 2048 + 2 * t];
    float4 vbn = V4[in_ * 2048 + 2 * t + 1];
    const float mn = smin[i];
    const float base = (1.0f - mn) * LOG2E;
    float vv[8] = {va.x, va.y, va.z, va.w, vb.x, vb.y, vb.z, vb.w};
    float e[8];
    float l = 0.0f;
#pragma unroll
    for (int k = 0; k < 8; ++k) {
      float zb = __builtin_fmaf(vv[k], LOG2E, base);
      e[k] = fast_exp2(zb * c[k]);
      l += e[k];
    }
#pragma unroll
    for (int off = 32; off; off >>= 1) l += __shfl_xor(l, off, 64);
    if (lane == 0) partials[s & 1][wave] = l;
    __syncthreads();
    float S = 0.0f;
#pragma unroll
    for (int w = 0; w < 16; ++w) S += partials[s & 1][w];
    const float Sinv = fast_rcp(S);
    float po[8] = {pa.x, pa.y, pa.z, pa.w, pb.x, pb.y, pb.z, pb.w};
    float o[8];
#pragma unroll
    for (int k = 0; k < 8; ++k) {
      float y = e[k] * Sinv;
      c[k] = __builtin_fmaf(-y, c[k], c[k]);
      o[k] = (r > 0) ? (po[k] + y) : y;
    }
    O4[i * 2048 + 2 * t]     = make_float4(o[0], o[1], o[2], o[3]);
    O4[i * 2048 + 2 * t + 1] = make_float4(o[4], o[5], o[6], o[7]);
    va = van; vb = vbn;
    pa = O4[in_ * 2048 + 2 * t];
    pb = O4[in_ * 2048 + 2 * t + 1];
  }
}

extern "C" void kernel_launch(void* const* d_in, const int* in_sizes, int n_in,
                              void* d_out, int out_size, void* d_ws, size_t ws_size,
                              hipStream_t stream) {
  const float* V = (const float*)d_in[0];
  float* out = (float*)d_out;
  float* rmin = (float*)d_ws;                                  // 4 KiB @ 0

  const size_t RING_OFF = 4096;                                // 2 KiB ring
  const size_t A_OFF    = 8192;
  const size_t A_BYTES  = (size_t)N_ROWS * M_COLS * 2;         // 16 MiB
  const size_t R_BYTES  = (size_t)STEPS * M_COLS * 2;          // 128 MiB
  const size_t need_mc  = A_OFF + A_BYTES + R_BYTES;           // ~144 MiB

  if (ws_size >= need_mc) {
    unsigned long long* ring = (unsigned long long*)((char*)d_ws + RING_OFF);
    __half* A = (__half*)((char*)d_ws + A_OFF);
    __half* R = (__half*)((char*)d_ws + A_OFF + A_BYTES);
    softrr_rowmin<<<N_ROWS, 256, 0, stream>>>(V, rmin);
    softrr_prep16<<<4096, 256, 0, stream>>>(V, rmin, A, ring);
    softrr_scan_mc<<<NBLK, TPB_MC, 0, stream>>>(A, R, ring);
    softrr_sum8<<<4096, 256, 0, stream>>>(R, out);
  } else {
    softrr_rowmin<<<N_ROWS, 256, 0, stream>>>(V, rmin);
    softrr_scan_b<<<1, 1024, 0, stream>>>(V, rmin, out);
  }
}

// Round 8
// 5957.726 us; speedup vs baseline: 2.5798x; 2.5798x over previous
//
#include <hip/hip_runtime.h>
#include <hip/hip_fp16.h>

// SoftRR: n=1024, m=8192, rounds=8, TAU=1.0
//   scan over 8192 rows (V tiled x8):
//     y = softmax((row - min(row) + 1) * c);  c = (1-y)*c
//   pi[i][j] = sum over rounds of y
//
// R12 (= R11 with legal asm): pk-f32 math + VGPR-pinned prefetch ring.
//   R6 (champion, 4157us scan): 16 waves x 8 cols, barrier sync, f16 A.
//   R8: pk math cut busy 1000->870 cy/step BUT VGPR_Count=32 proves the
//       f32 ring was evicted from VGPRs (AGPR copies) -> +180 cy stall.
//   R10: multi-CU sync = 4530 cy/step (LLC RT ~3300 cy). Single-CU only.
//   R11: failed to compile - "v" asm constraint illegal on float4 aggregates.
// R12 pins each 32-bit component individually ("+v"(v.x)...), which clang
// supports. Otherwise identical: R6 structure + pk math, barrier sync,
// padded sP, store-only R + sum8 epilogue.

#define N_ROWS 1024
#define M_COLS 8192
#define STEPS  8192
#define LOG2E  1.4426950408889634f

using half8  = __attribute__((ext_vector_type(8))) _Float16;
using half2v = __attribute__((ext_vector_type(2))) _Float16;
using float8 = __attribute__((ext_vector_type(8))) float;
using f32x2  = __attribute__((ext_vector_type(2))) float;

// pin a float4's components in VGPRs (zero-cost scheduling/regalloc fence)
#define PIN4(v) asm volatile("" : "+v"((v).x), "+v"((v).y), "+v"((v).z), "+v"((v).w))
#define USE4(v) asm volatile("" :: "v"((v).x), "v"((v).y), "v"((v).z), "v"((v).w))

__device__ __forceinline__ float fast_exp2(float x) {
#if __has_builtin(__builtin_amdgcn_exp2f)
  return __builtin_amdgcn_exp2f(x);
#else
  return exp2f(x);
#endif
}
__device__ __forceinline__ float fast_rcp(float x) {
#if __has_builtin(__builtin_amdgcn_rcpf)
  return __builtin_amdgcn_rcpf(x);
#else
  return 1.0f / x;
#endif
}
__device__ __forceinline__ unsigned pack_f16_u32(float y0, float y1) {
  return __builtin_bit_cast(unsigned, __builtin_amdgcn_cvt_pkrtz(y0, y1));
}
__device__ __forceinline__ f32x2 fma2(f32x2 a, f32x2 b, f32x2 c) {
#if __has_builtin(__builtin_elementwise_fma)
  return __builtin_elementwise_fma(a, b, c);
#else
  f32x2 r;
  r[0] = __builtin_fmaf(a[0], b[0], c[0]);
  r[1] = __builtin_fmaf(a[1], b[1], c[1]);
  return r;
#endif
}

template <int CTRL>
__device__ __forceinline__ float dpp_add(float x) {
  int yi = __builtin_amdgcn_update_dpp(0, __builtin_bit_cast(int, x),
                                       CTRL, 0xf, 0xf, true);
  return x + __builtin_bit_cast(float, yi);
}

// full 64-lane sum; result valid in lane 63
__device__ __forceinline__ float wave_sum_to_lane63(float x) {
  x = dpp_add<0x111>(x);
  x = dpp_add<0x112>(x);
  x = dpp_add<0x114>(x);
  x = dpp_add<0x118>(x);
  x = dpp_add<0x142>(x);
  x = dpp_add<0x143>(x);
  return x;
}

// barrier WITHOUT vmcnt drain: only LDS ops must be visible across it
#define BAR_LDS_ONLY() asm volatile("s_waitcnt lgkmcnt(0)\n\ts_barrier" ::: "memory")

// ---------------- rowmin: one block per row ----------------
__global__ void softrr_rowmin(const float* __restrict__ V, float* __restrict__ rmin) {
  const int row = blockIdx.x;
  const float* p = V + (size_t)row * M_COLS;
  float m = 1e30f;
  for (int j = threadIdx.x; j < M_COLS; j += 256) m = fminf(m, p[j]);
#pragma unroll
  for (int off = 32; off; off >>= 1) m = fminf(m, __shfl_xor(m, off, 64));
  __shared__ float sm[4];
  if ((threadIdx.x & 63) == 0) sm[threadIdx.x >> 6] = m;
  __syncthreads();
  if (threadIdx.x == 0) {
    rmin[row] = fminf(fminf(sm[0], sm[1]), fminf(sm[2], sm[3]));
  }
}

// ---------------- prep (f32): a = (V - rowmin + 1) * log2e ----------------
__global__ void softrr_prep_f32(const float* __restrict__ V, const float* __restrict__ rmin,
                                float* __restrict__ A) {
  const int idx8 = blockIdx.x * 256 + threadIdx.x;   // 1M float8 groups
  const int row = idx8 >> 10;
  const float mn = rmin[row];
  const float4* v4 = (const float4*)V;
  float4 va = v4[2 * idx8];
  float4 vb = v4[2 * idx8 + 1];
  float8 o;
  o[0] = (va.x - mn + 1.0f) * LOG2E;
  o[1] = (va.y - mn + 1.0f) * LOG2E;
  o[2] = (va.z - mn + 1.0f) * LOG2E;
  o[3] = (va.w - mn + 1.0f) * LOG2E;
  o[4] = (vb.x - mn + 1.0f) * LOG2E;
  o[5] = (vb.y - mn + 1.0f) * LOG2E;
  o[6] = (vb.z - mn + 1.0f) * LOG2E;
  o[7] = (vb.w - mn + 1.0f) * LOG2E;
  ((float8*)A)[idx8] = o;
}

// ---------------- prep (f16) for fallback path ----------------
__global__ void softrr_prep16(const float* __restrict__ V, const float* __restrict__ rmin,
                              __half* __restrict__ A) {
  const int idx8 = blockIdx.x * 256 + threadIdx.x;
  const int row = idx8 >> 10;
  const float mn = rmin[row];
  const float4* v4 = (const float4*)V;
  float4 va = v4[2 * idx8];
  float4 vb = v4[2 * idx8 + 1];
  half8 o;
  o[0] = (_Float16)((va.x - mn + 1.0f) * LOG2E);
  o[1] = (_Float16)((va.y - mn + 1.0f) * LOG2E);
  o[2] = (_Float16)((va.z - mn + 1.0f) * LOG2E);
  o[3] = (_Float16)((va.w - mn + 1.0f) * LOG2E);
  o[4] = (_Float16)((vb.x - mn + 1.0f) * LOG2E);
  o[5] = (_Float16)((vb.y - mn + 1.0f) * LOG2E);
  o[6] = (_Float16)((vb.z - mn + 1.0f) * LOG2E);
  o[7] = (_Float16)((vb.w - mn + 1.0f) * LOG2E);
  ((half8*)A)[idx8] = o;
}

// ---------------- R12 step body (pk math, pinned ring, barrier sync) -------
// On entry: e[] = e_s, o = packed y_{s-1}, sP[s&1] = partials of e_s,
// (ac0,ac1) = A row s+1. On exit: e[] = e_{s+1}, o = packed y_s,
// sP[(s&1)^1][wave] = partial of e_{s+1}; (ad0,ad1) <- A row s+3.
template <int PAR>
__device__ __forceinline__ void rr_step_pk(
    int s,
    float4& ac0, float4& ac1, float4& ad0, float4& ad1,
    f32x2 (&e)[4], f32x2 (&c)[4], uint4& o,
    const float4* __restrict__ A4, uint4* __restrict__ R4,
    float (*sP)[64], int t, int lane, int wave)
{
  // require the consumed A row to be sitting in VGPRs here (zero-cost)
  USE4(ac0); USE4(ac1);

  // head: issue the cross-wave partial read first (padded: no cndmask)
  float x = sP[PAR][lane];

  // window: store y_{s-1} (s=0 stores init garbage to row 8191, re-flushed)
  R4[(size_t)((s - 1) & (STEPS - 1)) * 1024 + t] = o;
  // window: prefetch A row s+3 (two dwordx4), pin results in VGPRs
  {
    const int ld = (s + 3) & (N_ROWS - 1);
    ad0 = A4[ld * 2048 + 2 * t];
    ad1 = A4[ld * 2048 + 2 * t + 1];
    PIN4(ad0); PIN4(ad1);
  }

  // finish cross-wave reduce -> Sinv (lanes 16..63 contribute zeros)
  x = dpp_add<0x111>(x);
  x = dpp_add<0x112>(x);
  x = dpp_add<0x114>(x);
  x = dpp_add<0x118>(x);   // lane15 = total of 16 partials
  const float S = __builtin_bit_cast(
      float, __builtin_amdgcn_readlane(__builtin_bit_cast(int, x), 15));
  const float Sinv = fast_rcp(S);
  const f32x2 Sv = {Sinv, Sinv};

  // chain (packed): y = e*Sinv; c' = fma(-y,c,c); t = a*c'; e' = exp2(t)
  const float av[8] = {ac0.x, ac0.y, ac0.z, ac0.w, ac1.x, ac1.y, ac1.z, ac1.w};
  f32x2 y[4];
#pragma unroll
  for (int k = 0; k < 4; ++k) {
    y[k] = e[k] * Sv;                        // v_pk_mul_f32
    c[k] = fma2(-y[k], c[k], c[k]);          // v_pk_fma_f32
    f32x2 a2 = {av[2 * k], av[2 * k + 1]};
    f32x2 tk = a2 * c[k];                    // v_pk_mul_f32
    e[k][0] = fast_exp2(tk[0]);
    e[k][1] = fast_exp2(tk[1]);
  }
  f32x2 s01 = e[0] + e[1];                   // v_pk_add_f32
  f32x2 s23 = e[2] + e[3];                   // v_pk_add_f32
  f32x2 s2  = s01 + s23;                     // v_pk_add_f32
  float l = s2[0] + s2[1];
  l = wave_sum_to_lane63(l);
  if (lane == 63) sP[PAR ^ 1][wave] = l;

  // tail: pack y_s into uint4 for next-step store
  o.x = pack_f16_u32(y[0][0], y[0][1]);
  o.y = pack_f16_u32(y[1][0], y[1][1]);
  o.z = pack_f16_u32(y[2][0], y[2][1]);
  o.w = pack_f16_u32(y[3][0], y[3][1]);
  BAR_LDS_ONLY();
}

// ---------------- main scan (R12): 1024 thr (16 waves), 8 cols/thread ------
__global__ void __launch_bounds__(1024) softrr_scan_pk(const float* __restrict__ Af,
                                                       __half* __restrict__ Rh) {
  const int t = threadIdx.x;          // 0..1023, owns cols 8t..8t+7
  const int wave = t >> 6;            // 0..15
  const int lane = t & 63;
  __shared__ float sP[2][64];         // padded: [16..63] stay zero

  const float4* __restrict__ A4 = (const float4*)Af;   // [1024][2048]
  uint4* __restrict__ R4 = (uint4*)Rh;

  if (t < 128) ((float*)sP)[t] = 0.0f;
  __syncthreads();

  f32x2 c[4], e[4];
#pragma unroll
  for (int k = 0; k < 4; ++k) c[k] = f32x2{1.0f, 1.0f};

  // prologue: row0 -> e_0; rows 1,2 into the A ring (float4 pairs)
  float4 r00 = A4[2 * t],        r01 = A4[2 * t + 1];
  float4 pA0 = A4[2048 + 2 * t], pA1 = A4[2048 + 2 * t + 1];   // row 1
  float4 pB0 = A4[4096 + 2 * t], pB1 = A4[4096 + 2 * t + 1];   // row 2
  float4 pC0, pC1, pD0, pD1;
  PIN4(pA0); PIN4(pA1); PIN4(pB0); PIN4(pB1);

  {
    const float rv[8] = {r00.x, r00.y, r00.z, r00.w, r01.x, r01.y, r01.z, r01.w};
#pragma unroll
    for (int k = 0; k < 4; ++k) {
      e[k][0] = fast_exp2(rv[2 * k]);       // c_0 = 1
      e[k][1] = fast_exp2(rv[2 * k + 1]);
    }
    f32x2 s01 = e[0] + e[1];
    f32x2 s23 = e[2] + e[3];
    f32x2 s2  = s01 + s23;
    float l = s2[0] + s2[1];
    l = wave_sum_to_lane63(l);
    if (lane == 63) sP[0][wave] = l;   // step 0 reads sP[0]
  }
  uint4 o = make_uint4(0u, 0u, 0u, 0u);  // garbage y_{-1}; only hits row 8191
  BAR_LDS_ONLY();

  // x4 unroll: A-buffer cycle period 4 -> zero rotation movs
  for (int s = 0; s < STEPS; s += 4) {
    rr_step_pk<0>(s + 0, pA0, pA1, pC0, pC1, e, c, o, A4, R4, sP, t, lane, wave);
    rr_step_pk<1>(s + 1, pB0, pB1, pD0, pD1, e, c, o, A4, R4, sP, t, lane, wave);
    rr_step_pk<0>(s + 2, pC0, pC1, pA0, pA1, e, c, o, A4, R4, sP, t, lane, wave);
    rr_step_pk<1>(s + 3, pD0, pD1, pB0, pB1, e, c, o, A4, R4, sP, t, lane, wave);
  }

  // flush y_{8191} (packed in o; also overwrites the s=0 garbage row)
  R4[(size_t)(STEPS - 1) * 1024 + t] = o;
}

// ---------------- R6 f16 scan (fallback for smaller ws) ----------------
__device__ __forceinline__ half2v pack_f16(float y0, float y1) {
  return __builtin_bit_cast(half2v, __builtin_amdgcn_cvt_pkrtz(y0, y1));
}

__device__ __forceinline__ void rr_step16(
    int s,
    const half8& acur, half8& adst,
    float (&e)[8], float (&c)[8], half8& o,
    const half8* __restrict__ A8, half8* __restrict__ R8,
    float (*sP)[16], int t, int lane, int wave)
{
  const int par = s & 1;
  float x = (lane < 16) ? sP[par][lane] : 0.0f;
  R8[(size_t)((s - 1) & (STEPS - 1)) * 1024 + t] = o;
  adst = A8[((s + 3) & (N_ROWS - 1)) * 1024 + t];
  x = dpp_add<0x111>(x);
  x = dpp_add<0x112>(x);
  x = dpp_add<0x114>(x);
  x = dpp_add<0x118>(x);
  const float S = __builtin_bit_cast(
      float, __builtin_amdgcn_readlane(__builtin_bit_cast(int, x), 15));
  const float Sinv = fast_rcp(S);
  float y[8];
#pragma unroll
  for (int k = 0; k < 8; ++k) {
    y[k] = e[k] * Sinv;
    c[k] = __builtin_fmaf(-y[k], c[k], c[k]);
    e[k] = fast_exp2(__builtin_fmaf((float)acur[k], c[k], 0.0f));
  }
  float l = ((e[0] + e[1]) + (e[2] + e[3])) + ((e[4] + e[5]) + (e[6] + e[7]));
  l = wave_sum_to_lane63(l);
  if (lane == 63) sP[par ^ 1][wave] = l;
  {
    half2v h0 = pack_f16(y[0], y[1]);
    half2v h1 = pack_f16(y[2], y[3]);
    half2v h2 = pack_f16(y[4], y[5]);
    half2v h3 = pack_f16(y[6], y[7]);
    o[0] = h0[0]; o[1] = h0[1]; o[2] = h1[0]; o[3] = h1[1];
    o[4] = h2[0]; o[5] = h2[1]; o[6] = h3[0]; o[7] = h3[1];
  }
  BAR_LDS_ONLY();
}

__global__ void __launch_bounds__(1024) softrr_scan_nor(const __half* __restrict__ Ah,
                                                        __half* __restrict__ Rh) {
  const int t = threadIdx.x;
  const int wave = t >> 6;
  const int lane = t & 63;
  __shared__ float sP[2][16];
  const half8* __restrict__ A8 = (const half8*)Ah;
  half8* __restrict__ R8 = (half8*)Rh;
  float c[8], e[8];
#pragma unroll
  for (int k = 0; k < 8; ++k) c[k] = 1.0f;
  half8 r0 = A8[t];
  half8 pA = A8[1024 + t];
  half8 pB = A8[2048 + t];
  half8 pC, pD;
#pragma unroll
  for (int k = 0; k < 8; ++k) e[k] = fast_exp2((float)r0[k]);
  {
    float l = ((e[0] + e[1]) + (e[2] + e[3])) + ((e[4] + e[5]) + (e[6] + e[7]));
    l = wave_sum_to_lane63(l);
    if (lane == 63) sP[0][wave] = l;
  }
  half8 o;
  {
    half2v z = pack_f16(0.0f, 0.0f);
    o[0]=z[0]; o[1]=z[1]; o[2]=z[0]; o[3]=z[1];
    o[4]=z[0]; o[5]=z[1]; o[6]=z[0]; o[7]=z[1];
  }
  BAR_LDS_ONLY();
  for (int s = 0; s < STEPS; s += 4) {
    rr_step16(s + 0, pA, pC, e, c, o, A8, R8, sP, t, lane, wave);
    rr_step16(s + 1, pB, pD, e, c, o, A8, R8, sP, t, lane, wave);
    rr_step16(s + 2, pC, pA, e, c, o, A8, R8, sP, t, lane, wave);
    rr_step16(s + 3, pD, pB, e, c, o, A8, R8, sP, t, lane, wave);
  }
  R8[(size_t)(STEPS - 1) * 1024 + t] = o;
}

// ---------------- epilogue: out[i][j] = sum_r R[r*1024+i][j] (f32) ----------------
__global__ void softrr_sum8(const __half* __restrict__ Rh, float* __restrict__ out) {
  const int idx8 = blockIdx.x * 256 + threadIdx.x;   // 1M half8 outputs
  const half8* R8 = (const half8*)Rh;
  float acc[8];
  {
    half8 v = R8[idx8];
#pragma unroll
    for (int k = 0; k < 8; ++k) acc[k] = (float)v[k];
  }
#pragma unroll
  for (int r = 1; r < 8; ++r) {
    half8 v = R8[(size_t)r * 1024 * 1024 + idx8];
#pragma unroll
    for (int k = 0; k < 8; ++k) acc[k] += (float)v[k];
  }
  ((float4*)out)[2 * idx8]     = make_float4(acc[0], acc[1], acc[2], acc[3]);
  ((float4*)out)[2 * idx8 + 1] = make_float4(acc[4], acc[5], acc[6], acc[7]);
}

// ---------------- fallback B: f32 direct (tiny ws) ----------------
__global__ void __launch_bounds__(1024) softrr_scan_b(const float* __restrict__ V,
                                                      const float* __restrict__ rmin,
                                                      float* __restrict__ out) {
  const int t = threadIdx.x;
  const int wave = t >> 6;
  const int lane = t & 63;
  __shared__ float partials[2][16];
  __shared__ float smin[N_ROWS];
  smin[t] = rmin[t];
  __syncthreads();
  const float4* __restrict__ V4 = (const float4*)V;
  float4* O4 = (float4*)out;
  float c[8];
#pragma unroll
  for (int k = 0; k < 8; ++k) c[k] = 1.0f;
  float4 va = V4[2 * t], vb = V4[2 * t + 1];
  float4 pa, pb;
  for (int s = 0; s < STEPS; ++s) {
    const int i = s & (N_ROWS - 1);
    const int r = s >> 10;
    const int in_ = (s + 1) & (N_ROWS - 1);
    float4 van = V4[in_ * 2048 + 2 * t];
    float4 vbn = V4[in_ * 2048 + 2 * t + 1];
    const float mn = smin[i];
    const float base = (1.0f - mn) * LOG2E;
    float vv[8] = {va.x, va.y, va.z, va.w, vb.x, vb.y, vb.z, vb.w};
    float e[8];
    float l = 0.0f;
#pragma unroll
    for (int k = 0; k < 8; ++k) {
      float zb = __builtin_fmaf(vv[k], LOG2E, base);
      e[k] = fast_exp2(zb * c[k]);
      l += e[k];
    }
#pragma unroll
    for (int off = 32; off; off >>= 1) l += __shfl_xor(l, off, 64);
    if (lane == 0) partials[s & 1][wave] = l;
    __syncthreads();
    float S = 0.0f;
#pragma unroll
    for (int w = 0; w < 16; ++w) S += partials[s & 1][w];
    const float Sinv = fast_rcp(S);
    float po[8] = {pa.x, pa.y, pa.z, pa.w, pb.x, pb.y, pb.z, pb.w};
    float o[8];
#pragma unroll
    for (int k = 0; k < 8; ++k) {
      float y = e[k] * Sinv;
      c[k] = __builtin_fmaf(-y, c[k], c[k]);
      o[k] = (r > 0) ? (po[k] + y) : y;
    }
    O4[i * 2048 + 2 * t]     = make_float4(o[0], o[1], o[2], o[3]);
    O4[i * 2048 + 2 * t + 1] = make_float4(o[4], o[5], o[6], o[7]);
    va = van; vb = vbn;
    pa = O4[in_ * 2048 + 2 * t];
    pb = O4[in_ * 2048 + 2 * t + 1];
  }
}

extern "C" void kernel_launch(void* const* d_in, const int* in_sizes, int n_in,
                              void* d_out, int out_size, void* d_ws, size_t ws_size,
                              hipStream_t stream) {
  const float* V = (const float*)d_in[0];
  float* out = (float*)d_out;
  float* rmin = (float*)d_ws;

  const size_t A16_BYTES = (size_t)N_ROWS * M_COLS * 2;        // 16 MiB
  const size_t A32_BYTES = (size_t)N_ROWS * M_COLS * 4;        // 32 MiB
  const size_t R_BYTES   = (size_t)STEPS * M_COLS * 2;         // 128 MiB
  const size_t need_f32  = 4096 + A32_BYTES + R_BYTES;         // ~160 MiB
  const size_t need_nor  = 4096 + A16_BYTES + R_BYTES;         // ~144 MiB

  if (ws_size >= need_f32) {
    float*  A = (float*)((char*)d_ws + 4096);
    __half* R = (__half*)((char*)d_ws + 4096 + A32_BYTES);
    softrr_rowmin<<<N_ROWS, 256, 0, stream>>>(V, rmin);
    softrr_prep_f32<<<4096, 256, 0, stream>>>(V, rmin, A);
    softrr_scan_pk<<<1, 1024, 0, stream>>>(A, R);
    softrr_sum8<<<4096, 256, 0, stream>>>(R, out);
  } else if (ws_size >= need_nor) {
    __half* A = (__half*)((char*)d_ws + 4096);
    __half* R = (__half*)((char*)d_ws + 4096 + A16_BYTES);
    softrr_rowmin<<<N_ROWS, 256, 0, stream>>>(V, rmin);
    softrr_prep16<<<4096, 256, 0, stream>>>(V, rmin, A);
    softrr_scan_nor<<<1, 1024, 0, stream>>>(A, R);
    softrr_sum8<<<4096, 256, 0, stream>>>(R, out);
  } else {
    softrr_rowmin<<<N_ROWS, 256, 0, stream>>>(V, rmin);
    softrr_scan_b<<<1, 1024, 0, stream>>>(V, rmin, out);
  }
}

// Round 9
// 4282.169 us; speedup vs baseline: 3.5892x; 1.3913x over previous
//
#include <hip/hip_runtime.h>
#include <hip/hip_fp16.h>

// SoftRR: n=1024, m=8192, rounds=8, TAU=1.0
//   scan over 8192 rows (V tiled x8):
//     y = softmax((row - min(row) + 1) * c);  c = (1-y)*c
//   pi[i][j] = sum over rounds of y
//
// R13 = exact revert to the R6 champion (scan 4157us, total 4288us).
// Experiment ledger vs R6 (all regressed or null):
//   R5  chain restructure (one-step y deferral)      null
//   R7  LDS-atomic S-reduce (same-addr ds_add ring)  -5%  (atomic serialize)
//   R8  pk-f32 math + f32 A                          -4%  (ring evicted, stall)
//   R9  barrier-free tagged-slot dataflow            -4.5% (poll issue)
//   R10 multi-CU 16-block dataflow                   -270% (LLC RT ~3300 cy)
//   R12 pk + per-component asm pins                  -41% (pins = sched fences)
// Structure: 16 waves x 8 cols, barrier sync (lgkmcnt-only), f16 A,
// prefetch 3 ahead (4-buffer rotation), store-only R[8192][8192] f16,
// full-chip sum8 epilogue. Step = 1218 cy ~= 1000 issue-busy (82% VALU on
// the active CU) + ~220 sync tail; issue-reduction attempts trade 1:1 into
// stall, sync-structure attempts null/negative, cross-CU dead. This is the
// measured structural floor of a serial 8192-step single-CU scan here.

#define N_ROWS 1024
#define M_COLS 8192
#define STEPS  8192
#define LOG2E  1.4426950408889634f

using half8  = __attribute__((ext_vector_type(8))) _Float16;
using half2v = __attribute__((ext_vector_type(2))) _Float16;

__device__ __forceinline__ float fast_exp2(float x) {
#if __has_builtin(__builtin_amdgcn_exp2f)
  return __builtin_amdgcn_exp2f(x);
#else
  return exp2f(x);
#endif
}
__device__ __forceinline__ float fast_rcp(float x) {
#if __has_builtin(__builtin_amdgcn_rcpf)
  return __builtin_amdgcn_rcpf(x);
#else
  return 1.0f / x;
#endif
}
__device__ __forceinline__ half2v pack_f16(float y0, float y1) {
  return __builtin_bit_cast(half2v, __builtin_amdgcn_cvt_pkrtz(y0, y1));
}

template <int CTRL>
__device__ __forceinline__ float dpp_add(float x) {
  int yi = __builtin_amdgcn_update_dpp(0, __builtin_bit_cast(int, x),
                                       CTRL, 0xf, 0xf, true);
  return x + __builtin_bit_cast(float, yi);
}

// full 64-lane sum; result valid in lane 63
__device__ __forceinline__ float wave_sum_to_lane63(float x) {
  x = dpp_add<0x111>(x);  // row_shr:1
  x = dpp_add<0x112>(x);  // row_shr:2
  x = dpp_add<0x114>(x);  // row_shr:4
  x = dpp_add<0x118>(x);  // row_shr:8   -> lane15 of each row = row sum
  x = dpp_add<0x142>(x);  // row_bcast15
  x = dpp_add<0x143>(x);  // row_bcast31 -> lane63 = total
  return x;
}

// barrier WITHOUT vmcnt drain: only LDS ops must be visible across it
#define BAR_LDS_ONLY() asm volatile("s_waitcnt lgkmcnt(0)\n\ts_barrier" ::: "memory")

// ---------------- rowmin: one block per row ----------------
__global__ void softrr_rowmin(const float* __restrict__ V, float* __restrict__ rmin) {
  const int row = blockIdx.x;
  const float* p = V + (size_t)row * M_COLS;
  float m = 1e30f;
  for (int j = threadIdx.x; j < M_COLS; j += 256) m = fminf(m, p[j]);
#pragma unroll
  for (int off = 32; off; off >>= 1) m = fminf(m, __shfl_xor(m, off, 64));
  __shared__ float sm[4];
  if ((threadIdx.x & 63) == 0) sm[threadIdx.x >> 6] = m;
  __syncthreads();
  if (threadIdx.x == 0) {
    rmin[row] = fminf(fminf(sm[0], sm[1]), fminf(sm[2], sm[3]));
  }
}

// ---------------- prep: a = (V - rowmin + 1) * log2e, fp16 ----------------
__global__ void softrr_prep16(const float* __restrict__ V, const float* __restrict__ rmin,
                              __half* __restrict__ A) {
  const int idx8 = blockIdx.x * 256 + threadIdx.x;   // 1M half8 groups
  const int row = idx8 >> 10;                        // 1024 half8 per row
  const float mn = rmin[row];
  const float4* v4 = (const float4*)V;
  float4 va = v4[2 * idx8];
  float4 vb = v4[2 * idx8 + 1];
  half8 o;
  o[0] = (_Float16)((va.x - mn + 1.0f) * LOG2E);
  o[1] = (_Float16)((va.y - mn + 1.0f) * LOG2E);
  o[2] = (_Float16)((va.z - mn + 1.0f) * LOG2E);
  o[3] = (_Float16)((va.w - mn + 1.0f) * LOG2E);
  o[4] = (_Float16)((vb.x - mn + 1.0f) * LOG2E);
  o[5] = (_Float16)((vb.y - mn + 1.0f) * LOG2E);
  o[6] = (_Float16)((vb.z - mn + 1.0f) * LOG2E);
  o[7] = (_Float16)((vb.w - mn + 1.0f) * LOG2E);
  ((half8*)A)[idx8] = o;
}

// ---------------- R6 step body (champion) ----------------
// On entry: e[] = e_s, o = packed y_{s-1}, sP[s&1] = partials of e_s,
// acur = A row (s+1). On exit: e[] = e_{s+1}, o = packed y_s,
// sP[(s&1)^1] = partials of e_{s+1}; adst <- A row (s+3).
__device__ __forceinline__ void rr_step16(
    int s,
    const half8& acur, half8& adst,
    float (&e)[8], float (&c)[8], half8& o,
    const half8* __restrict__ A8, half8* __restrict__ R8,
    float (*sP)[16], int t, int lane, int wave)
{
  const int par = s & 1;
  // issue the cross-wave partial read first; latency hidden by window work
  float x = (lane < 16) ? sP[par][lane] : 0.0f;

  // ---- window: store y_{s-1} (s=0 stores init garbage to row 8191,
  //      overwritten by the post-loop flush) ----
  R8[(size_t)((s - 1) & (STEPS - 1)) * 1024 + t] = o;

  // ---- window: prefetch A row s+3 ----
  adst = A8[((s + 3) & (N_ROWS - 1)) * 1024 + t];

  // ---- finish cross-wave reduce -> Sinv ----
  x = dpp_add<0x111>(x);
  x = dpp_add<0x112>(x);
  x = dpp_add<0x114>(x);
  x = dpp_add<0x118>(x);   // lane15 = total of 16 partials
  const float S = __builtin_bit_cast(
      float, __builtin_amdgcn_readlane(__builtin_bit_cast(int, x), 15));
  const float Sinv = fast_rcp(S);

  // ---- chain: y = e*Sinv; c' = c - y*c; e' = exp2(a*c') ----
  float y[8];
#pragma unroll
  for (int k = 0; k < 8; ++k) {
    y[k] = e[k] * Sinv;
    c[k] = __builtin_fmaf(-y[k], c[k], c[k]);
    e[k] = fast_exp2(__builtin_fmaf((float)acur[k], c[k], 0.0f));  // v_fma_mix
  }
  float l = ((e[0] + e[1]) + (e[2] + e[3])) + ((e[4] + e[5]) + (e[6] + e[7]));
  l = wave_sum_to_lane63(l);
  if (lane == 63) sP[par ^ 1][wave] = l;

  // ---- tail (dead time before barrier): pack y_s for next-step store ----
  {
    half2v h0 = pack_f16(y[0], y[1]);
    half2v h1 = pack_f16(y[2], y[3]);
    half2v h2 = pack_f16(y[4], y[5]);
    half2v h3 = pack_f16(y[6], y[7]);
    o[0] = h0[0]; o[1] = h0[1]; o[2] = h1[0]; o[3] = h1[1];
    o[4] = h2[0]; o[5] = h2[1]; o[6] = h3[0]; o[7] = h3[1];
  }
  BAR_LDS_ONLY();
}

// ---------------- main scan, store-only: 1024 thr (16 waves), 8 cols/thread ----
__global__ void __launch_bounds__(1024) softrr_scan_nor(const __half* __restrict__ Ah,
                                                        __half* __restrict__ Rh) {
  const int t = threadIdx.x;          // 0..1023, owns cols 8t..8t+7
  const int wave = t >> 6;            // 0..15
  const int lane = t & 63;
  __shared__ float sP[2][16];

  const half8* __restrict__ A8 = (const half8*)Ah;
  half8* __restrict__ R8 = (half8*)Rh;

  float c[8], e[8];
#pragma unroll
  for (int k = 0; k < 8; ++k) c[k] = 1.0f;

  // prologue: row0 -> e_0; rows 1,2 into the A ring
  half8 r0 = A8[t];
  half8 pA = A8[1024 + t];    // row 1
  half8 pB = A8[2048 + t];    // row 2
  half8 pC, pD;

#pragma unroll
  for (int k = 0; k < 8; ++k) e[k] = fast_exp2((float)r0[k]);   // c_0 = 1
  {
    float l = ((e[0] + e[1]) + (e[2] + e[3])) + ((e[4] + e[5]) + (e[6] + e[7]));
    l = wave_sum_to_lane63(l);
    if (lane == 63) sP[0][wave] = l;
  }
  half8 o;   // packed y_{s-1}; init value only reaches row 8191 (re-flushed)
  {
    half2v z = pack_f16(0.0f, 0.0f);
    o[0]=z[0]; o[1]=z[1]; o[2]=z[0]; o[3]=z[1];
    o[4]=z[0]; o[5]=z[1]; o[6]=z[0]; o[7]=z[1];
  }
  BAR_LDS_ONLY();

  // x4 unroll: A-buffer cycle period 4 -> zero rotation movs
  for (int s = 0; s < STEPS; s += 4) {
    rr_step16(s + 0, pA, pC, e, c, o, A8, R8, sP, t, lane, wave);
    rr_step16(s + 1, pB, pD, e, c, o, A8, R8, sP, t, lane, wave);
    rr_step16(s + 2, pC, pA, e, c, o, A8, R8, sP, t, lane, wave);
    rr_step16(s + 3, pD, pB, e, c, o, A8, R8, sP, t, lane, wave);
  }

  // flush y_{8191} (lives packed in o; also overwrites the s=0 garbage row)
  R8[(size_t)(STEPS - 1) * 1024 + t] = o;
}

// ---------------- epilogue: out[i][j] = sum_r R[r*1024+i][j] (f32) ----------------
__global__ void softrr_sum8(const __half* __restrict__ Rh, float* __restrict__ out) {
  const int idx8 = blockIdx.x * 256 + threadIdx.x;   // 1M half8 outputs
  const half8* R8 = (const half8*)Rh;
  float acc[8];
  {
    half8 v = R8[idx8];
#pragma unroll
    for (int k = 0; k < 8; ++k) acc[k] = (float)v[k];
  }
#pragma unroll
  for (int r = 1; r < 8; ++r) {
    half8 v = R8[(size_t)r * 1024 * 1024 + idx8];
#pragma unroll
    for (int k = 0; k < 8; ++k) acc[k] += (float)v[k];
  }
  ((float4*)out)[2 * idx8]     = make_float4(acc[0], acc[1], acc[2], acc[3]);
  ((float4*)out)[2 * idx8 + 1] = make_float4(acc[4], acc[5], acc[6], acc[7]);
}

// ---------------- fallback B: f32 direct (tiny ws) ----------------
__global__ void __launch_bounds__(1024) softrr_scan_b(const float* __restrict__ V,
                                                      const float* __restrict__ rmin,
                                                      float* __restrict__ out) {
  const int t = threadIdx.x;
  const int wave = t >> 6;
  const int lane = t & 63;
  __shared__ float partials[2][16];
  __shared__ float smin[N_ROWS];
  smin[t] = rmin[t];
  __syncthreads();
  const float4* __restrict__ V4 = (const float4*)V;
  float4* O4 = (float4*)out;
  float c[8];
#pragma unroll
  for (int k = 0; k < 8; ++k) c[k] = 1.0f;
  float4 va = V4[2 * t], vb = V4[2 * t + 1];
  float4 pa, pb;
  for (int s = 0; s < STEPS; ++s) {
    const int i = s & (N_ROWS - 1);
    const int r = s >> 10;
    const int in_ = (s + 1) & (N_ROWS - 1);
    float4 van = V4[in_ * 2048 + 2 * t];
    float4 vbn = V4[in_ * 2048 + 2 * t + 1];
    const float mn = smin[i];
    const float base = (1.0f - mn) * LOG2E;
    float vv[8] = {va.x, va.y, va.z, va.w, vb.x, vb.y, vb.z, vb.w};
    float e[8];
    float l = 0.0f;
#pragma unroll
    for (int k = 0; k < 8; ++k) {
      float zb = __builtin_fmaf(vv[k], LOG2E, base);
      e[k] = fast_exp2(zb * c[k]);
      l += e[k];
    }
#pragma unroll
    for (int off = 32; off; off >>= 1) l += __shfl_xor(l, off, 64);
    if (lane == 0) partials[s & 1][wave] = l;
    __syncthreads();
    float S = 0.0f;
#pragma unroll
    for (int w = 0; w < 16; ++w) S += partials[s & 1][w];
    const float Sinv = fast_rcp(S);
    float po[8] = {pa.x, pa.y, pa.z, pa.w, pb.x, pb.y, pb.z, pb.w};
    float o[8];
#pragma unroll
    for (int k = 0; k < 8; ++k) {
      float y = e[k] * Sinv;
      c[k] = __builtin_fmaf(-y, c[k], c[k]);
      o[k] = (r > 0) ? (po[k] + y) : y;
    }
    O4[i * 2048 + 2 * t]     = make_float4(o[0], o[1], o[2], o[3]);
    O4[i * 2048 + 2 * t + 1] = make_float4(o[4], o[5], o[6], o[7]);
    va = van; vb = vbn;
    pa = O4[in_ * 2048 + 2 * t];
    pb = O4[in_ * 2048 + 2 * t + 1];
  }
}

extern "C" void kernel_launch(void* const* d_in, const int* in_sizes, int n_in,
                              void* d_out, int out_size, void* d_ws, size_t ws_size,
                              hipStream_t stream) {
  const float* V = (const float*)d_in[0];
  float* out = (float*)d_out;
  float* rmin = (float*)d_ws;

  const size_t A_BYTES = (size_t)N_ROWS * M_COLS * 2;          // 16 MiB
  const size_t R_BYTES = (size_t)STEPS * M_COLS * 2;           // 128 MiB
  const size_t need_nor = 4096 + A_BYTES + R_BYTES;            // ~144 MiB

  if (ws_size >= need_nor) {
    __half* A = (__half*)((char*)d_ws + 4096);
    __half* R = (__half*)((char*)d_ws + 4096 + A_BYTES);
    softrr_rowmin<<<N_ROWS, 256, 0, stream>>>(V, rmin);
    softrr_prep16<<<4096, 256, 0, stream>>>(V, rmin, A);
    softrr_scan_nor<<<1, 1024, 0, stream>>>(A, R);
    softrr_sum8<<<4096, 256, 0, stream>>>(R, out);
  } else {
    softrr_rowmin<<<N_ROWS, 256, 0, stream>>>(V, rmin);
    softrr_scan_b<<<1, 1024, 0, stream>>>(V, rmin, out);
  }
}